// Round 7
// baseline (84.406 us; speedup 1.0000x reference)
//
#include <hip/hip_runtime.h>
#include <hip/hip_bf16.h>

#define NROWS 8192
#define DIM   256
#define WROWS 64                   // rows per wave (A fully in registers)
#define NT    16                   // 16-col tiles per wave -> 256 cols/wave
// zk stores z * SQ_SCALE, SQ_SCALE^2 = 10*log2(e) -> MFMA gives 14.43*cos,
// so exp(sim) = exp2(mfma_out) directly.
#define SQ_SCALE 3.798282387f
#define LN2      0.69314718056f    // 10 / 14.4269504089

typedef __attribute__((ext_vector_type(8))) short short8;
typedef __attribute__((ext_vector_type(4))) float f32x4;

__device__ __forceinline__ float bfbits2f(unsigned short u) {
    unsigned int x = ((unsigned int)u) << 16;
    float f; __builtin_memcpy(&f, &x, 4); return f;
}
__device__ __forceinline__ unsigned short f2bf(float x) {
    __hip_bfloat16 h = __float2bfloat16(x);
    unsigned short u; __builtin_memcpy(&u, &h, 2); return u;
}

// ---------------------------------------------------------------------------
// Kernel 1: L2-normalize rows fp32 -> bf16*SQ_SCALE into the fragment-native
// K-major layout: (row,d) -> (row>>4)*4096 + (d>>5)*512 + ((d>>3)&3)*128
//                           + (row&15)*8 + (d&7).
// Also: exact rounded self-dot sd[row] = sum(z_bf^2) (fp32) and label hist.
// ---------------------------------------------------------------------------
__global__ __launch_bounds__(256)
void normalize_kernel(const float* __restrict__ latent,
                      const int* __restrict__ labels,
                      unsigned short* __restrict__ zk,
                      float* __restrict__ sd_out,
                      int* __restrict__ hist) {
    const int wave = threadIdx.x >> 6, lane = threadIdx.x & 63;
    const int row = blockIdx.x * 4 + wave;
    const float4 v = ((const float4*)(latent + (size_t)row * DIM))[lane];
    float s = v.x * v.x + v.y * v.y + v.z * v.z + v.w * v.w;
    #pragma unroll
    for (int m = 32; m; m >>= 1) s += __shfl_xor(s, m, 64);
    const float sc = rsqrtf(s) * SQ_SCALE;
    ushort4 o;
    o.x = f2bf(v.x * sc); o.y = f2bf(v.y * sc);
    o.z = f2bf(v.z * sc); o.w = f2bf(v.w * sc);
    const int d0 = lane * 4;
    const size_t idx = (size_t)(row >> 4) * 4096 + (d0 >> 5) * 512
                     + ((d0 >> 3) & 3) * 128 + (row & 15) * 8 + (d0 & 7);
    *(ushort4*)(zk + idx) = o;
    // exact self-dot of the ROUNDED values (what the MFMA diagonal computes)
    const float r0 = bfbits2f(o.x), r1 = bfbits2f(o.y),
                r2 = bfbits2f(o.z), r3 = bfbits2f(o.w);
    float sd = r0 * r0 + r1 * r1 + r2 * r2 + r3 * r3;
    #pragma unroll
    for (int m = 32; m; m >>= 1) sd += __shfl_xor(sd, m, 64);
    if (lane == 0) {
        sd_out[row] = sd;
        atomicAdd(&hist[labels[row]], 1);
    }
}

// ---------------------------------------------------------------------------
// Kernel 2: fused sim reductions, registers only, no barriers in the sweep.
// 256 thr = 4 waves sharing the block's 64 rows (A = 128 VGPR), each wave
// sweeps a different 256-col strip. No diagonal handling (self term removed
// exactly in the final pass). rb-major XCD pinning: bid&7 == rb&7 keeps a
// 512 KB A working set hot per XCD L2.
// ---------------------------------------------------------------------------
__global__ __launch_bounds__(256, 2)
void ntxent_main(const unsigned short* __restrict__ zk,
                 const int* __restrict__ labels,
                 float* __restrict__ se_sum,
                 float* __restrict__ ps_sum) {
    __shared__ float rse[WROWS], rps[WROWS];
    const int tid  = threadIdx.x;
    const int wave = tid >> 6, lane = tid & 63;
    const int lrow = lane & 15, kgrp = lane >> 4;
    const int rb = blockIdx.x & 127, cb = blockIdx.x >> 7;   // XCD = bid%8 = rb%8
    const int rowW = rb * WROWS;
    const int strip = cb * 4 + wave;                          // 0..31
    const int colStart = strip * 256;

    if (tid < WROWS) { rse[tid] = 0.f; rps[tid] = 0.f; }

    // --- A fragments: 4 row-tiles x 8 k-chunks, contiguous 16B/lane ---
    short8 a[4][8];
    #pragma unroll
    for (int q = 0; q < 4; ++q) {
        const unsigned short* base = zk + (size_t)(rb * 4 + q) * 4096 + lane * 8;
        #pragma unroll
        for (int kk = 0; kk < 8; ++kk) a[q][kk] = *(const short8*)(base + kk * 512);
    }
    int labr[16];
    #pragma unroll
    for (int q = 0; q < 4; ++q)
        #pragma unroll
        for (int j = 0; j < 4; ++j)
            labr[q * 4 + j] = labels[rowW + q * 16 + kgrp * 4 + j];

    float se[16], ps[16];
    #pragma unroll
    for (int i = 0; i < 16; ++i) { se[i] = 0.f; ps[i] = 0.f; }

    const unsigned short* bbase = zk + (size_t)(strip * 16) * 4096 + lane * 8;
    short8 b[8];
    #pragma unroll
    for (int kk = 0; kk < 8; ++kk) b[kk] = *(const short8*)(bbase + kk * 512);

    #pragma unroll 1
    for (int t = 0; t < NT; ++t) {
        const int labc = labels[colStart + t * 16 + lrow];   // hidden under MFMAs
        f32x4 c[4];
        #pragma unroll
        for (int q = 0; q < 4; ++q) c[q] = (f32x4){0.f, 0.f, 0.f, 0.f};
        __builtin_amdgcn_s_setprio(1);
        #pragma unroll
        for (int kk = 0; kk < 8; ++kk) {
            c[0] = __builtin_amdgcn_mfma_f32_16x16x32_bf16(a[0][kk], b[kk], c[0], 0, 0, 0);
            c[1] = __builtin_amdgcn_mfma_f32_16x16x32_bf16(a[1][kk], b[kk], c[1], 0, 0, 0);
            c[2] = __builtin_amdgcn_mfma_f32_16x16x32_bf16(a[2][kk], b[kk], c[2], 0, 0, 0);
            c[3] = __builtin_amdgcn_mfma_f32_16x16x32_bf16(a[3][kk], b[kk], c[3], 0, 0, 0);
        }
        __builtin_amdgcn_s_setprio(0);
        // prefetch next B tile (WAR after last use; latency hides under epilogue)
        if (t + 1 < NT) {
            const unsigned short* nb = bbase + (size_t)(t + 1) * 4096;
            #pragma unroll
            for (int kk = 0; kk < 8; ++kk) b[kk] = *(const short8*)(nb + kk * 512);
        }
        // lean epilogue: exp2+add (se) and cndmask+add (ps). No diag handling.
        #pragma unroll
        for (int q = 0; q < 4; ++q)
            #pragma unroll
            for (int j = 0; j < 4; ++j) {
                const int i = q * 4 + j;
                se[i] += exp2f(c[q][j]);
                ps[i] += (labc == labr[i]) ? c[q][j] : 0.f;  // incl self; fixed later
            }
    }

    // --- reduce over the 16 col-lanes of each kgrp group ---
    #pragma unroll
    for (int i = 0; i < 16; ++i) {
        #pragma unroll
        for (int m = 1; m < 16; m <<= 1) {
            se[i] += __shfl_xor(se[i], m, 64);
            ps[i] += __shfl_xor(ps[i], m, 64);
        }
    }
    __syncthreads();                 // rse/rps init done
    if (lrow == 0) {
        #pragma unroll
        for (int i = 0; i < 16; ++i) {
            const int rl = (i >> 2) * 16 + kgrp * 4 + (i & 3);
            atomicAdd(&rse[rl], se[i]);
            atomicAdd(&rps[rl], ps[i]);
        }
    }
    __syncthreads();
    if (tid < WROWS) {
        atomicAdd(&se_sum[rowW + tid], rse[tid]);
        atomicAdd(&ps_sum[rowW + tid], rps[tid]);
    }
}

// ---------------------------------------------------------------------------
// Kernel 3: parallel finalize. Per row: subtract exact self terms,
// loss_r = log(se - exp2(sd)) - LN2*(ps - sd)/n_pos. 32 blocks x 256 thr.
// ---------------------------------------------------------------------------
__global__ __launch_bounds__(256)
void ntxent_final(const float* __restrict__ se_sum,
                  const float* __restrict__ ps_sum,
                  const float* __restrict__ sd,
                  const int* __restrict__ labels,
                  const int* __restrict__ hist,
                  float* __restrict__ acc) {
    __shared__ float rc[4], rh[4];
    const int tid = threadIdx.x;
    const int r = blockIdx.x * 256 + tid;
    const int lab = labels[r];
    const int n = hist[lab] - 1;
    float contrib = 0.f, hp = 0.f;
    if (n > 0) {
        const float s  = sd[r];
        const float se = se_sum[r] - exp2f(s);       // remove self exactly
        const float lse  = __logf(se);
        const float mean = LN2 * (ps_sum[r] - s) / (float)n;
        contrib = lse - mean;
        hp = 1.0f;
    }
    #pragma unroll
    for (int m = 32; m; m >>= 1) {
        contrib += __shfl_xor(contrib, m, 64);
        hp      += __shfl_xor(hp, m, 64);
    }
    if ((tid & 63) == 0) { rc[tid >> 6] = contrib; rh[tid >> 6] = hp; }
    __syncthreads();
    if (tid == 0) {
        atomicAdd(&acc[0], rc[0] + rc[1] + rc[2] + rc[3]);
        atomicAdd(&acc[1], rh[0] + rh[1] + rh[2] + rh[3]);
    }
}

__global__ void finalize_kernel(const float* __restrict__ acc,
                                float* __restrict__ out) {
    out[0] = acc[0] / fmaxf(acc[1], 1.0f);
}

extern "C" void kernel_launch(void* const* d_in, const int* in_sizes, int n_in,
                              void* d_out, int out_size, void* d_ws, size_t ws_size,
                              hipStream_t stream) {
    const float* latent = (const float*)d_in[0];
    const int*   labels = (const int*)d_in[1];
    float* out = (float*)d_out;

    unsigned short* zk = (unsigned short*)d_ws;                       // 4 MB
    char* p = (char*)d_ws + (size_t)NROWS * DIM * sizeof(unsigned short);
    float* se_sum = (float*)p;                                        // 32 KB
    float* ps_sum = (float*)(p + 32768);                              // 32 KB
    float* sd     = (float*)(p + 65536);                              // 32 KB
    int*   hist   = (int*)  (p + 98304);                              // 512 B
    float* acc    = (float*)(p + 98304 + 512);                        // 8 B

    hipMemsetAsync(p, 0, 98304 + 512 + 8, stream);
    normalize_kernel<<<NROWS / 4, 256, 0, stream>>>(latent, labels, zk, sd, hist);
    ntxent_main<<<1024, 256, 0, stream>>>(zk, labels, se_sum, ps_sum);
    ntxent_final<<<NROWS / 256, 256, 0, stream>>>(se_sum, ps_sum, sd, labels, hist, acc);
    finalize_kernel<<<1, 1, 0, stream>>>(acc, out);
}

// Round 9
// 77.469 us; speedup vs baseline: 1.0895x; 1.0895x over previous
//
#include <hip/hip_runtime.h>
#include <hip/hip_bf16.h>

#define NROWS 8192
#define DIM   256
// zk stores z * SQ_SCALE, SQ_SCALE^2 = 10*log2(e) -> MFMA yields 14.43*cos,
// so exp(sim) = exp2(mfma_out) directly (exp2f == v_exp_f32 on amdgcn).
#define SQ_SCALE 3.798282387f
#define LN2      0.69314718056f    // 10 / 14.4269504089

typedef __attribute__((ext_vector_type(8))) short short8;
typedef __attribute__((ext_vector_type(4))) float f32x4;

__device__ __forceinline__ float bfbits2f(unsigned short u) {
    unsigned int x = ((unsigned int)u) << 16;
    float f; __builtin_memcpy(&f, &x, 4); return f;
}
__device__ __forceinline__ unsigned short f2bf(float x) {
    __hip_bfloat16 h = __float2bfloat16(x);
    unsigned short u; __builtin_memcpy(&u, &h, 2); return u;
}

// Phase boundary: drain own counters, barrier, then FENCE THE COMPILER on the
// far side (s_barrier is IntrNoMem -- without the trailing fence, hipcc may
// hoist next-phase LDS reads above the barrier; that was round 8's NaN).
__device__ __forceinline__ void phase_barrier() {
    asm volatile("s_waitcnt vmcnt(0) lgkmcnt(0)" ::: "memory");
    __builtin_amdgcn_s_barrier();
    asm volatile("" ::: "memory");
    __builtin_amdgcn_sched_barrier(0);
}

// ---------------------------------------------------------------------------
// Kernel 1: L2-normalize rows fp32 -> bf16*SQ_SCALE into the fragment-native
// K-major layout: (row,d) -> (row>>4)*4096 + (d>>5)*512 + ((d>>3)&3)*128
//                           + (row&15)*8 + (d&7).
// Also stores the exact rounded self-dot sd[row] (fp32). No atomics.
// ---------------------------------------------------------------------------
__global__ __launch_bounds__(256)
void normalize_kernel(const float* __restrict__ latent,
                      unsigned short* __restrict__ zk,
                      float* __restrict__ sd_out) {
    const int wave = threadIdx.x >> 6, lane = threadIdx.x & 63;
    const int row = blockIdx.x * 4 + wave;
    const float4 v = ((const float4*)(latent + (size_t)row * DIM))[lane];
    float s = v.x * v.x + v.y * v.y + v.z * v.z + v.w * v.w;
    #pragma unroll
    for (int m = 32; m; m >>= 1) s += __shfl_xor(s, m, 64);
    const float sc = rsqrtf(s) * SQ_SCALE;
    ushort4 o;
    o.x = f2bf(v.x * sc); o.y = f2bf(v.y * sc);
    o.z = f2bf(v.z * sc); o.w = f2bf(v.w * sc);
    const int d0 = lane * 4;
    const size_t idx = (size_t)(row >> 4) * 4096 + (d0 >> 5) * 512
                     + ((d0 >> 3) & 3) * 128 + (row & 15) * 8 + (d0 & 7);
    *(ushort4*)(zk + idx) = o;
    const float r0 = bfbits2f(o.x), r1 = bfbits2f(o.y),
                r2 = bfbits2f(o.z), r3 = bfbits2f(o.w);
    float sd = r0 * r0 + r1 * r1 + r2 * r2 + r3 * r3;
    #pragma unroll
    for (int m = 32; m; m >>= 1) sd += __shfl_xor(sd, m, 64);
    if (lane == 0) sd_out[row] = sd;
}

// ---------------------------------------------------------------------------
// Kernel 2: flash-style fused sim reductions.
// 256 thr = 4 waves; wave owns 64 rows (A = 128 VGPR). Block sweeps 512 cols
// as 8 x 64-col tiles; each tile (32 KB, contiguous in zk's fragment layout)
// is staged ONCE via global_load_lds into double-buffered LDS and shared by
// all 4 waves. One fully-drained barrier per phase; issue-early staging (T14).
// No diag handling in-loop (self removed exactly in final). Packed row labels.
// Grid = 32 rowgroups x 16 colsplits = 512 blocks = exactly 2/CU resident.
// ---------------------------------------------------------------------------
__global__ __launch_bounds__(256, 2)
void ntxent_main(const unsigned short* __restrict__ zk,
                 const int* __restrict__ labels,
                 float* __restrict__ se_sum,
                 float* __restrict__ ps_sum) {
    __shared__ __align__(16) char ldsB[2 * 32768];   // double-buffered 64-col tile
    __shared__ int ldsLab[512];

    const int tid  = threadIdx.x;
    const int wave = tid >> 6, lane = tid & 63;
    const int lrow = lane & 15, kgrp = lane >> 4;
    const int cs = blockIdx.x & 15, rb = blockIdx.x >> 4;  // XCD = bid%8 = cs%8
    const int colStart = cs * 512;
    const int rowW = rb * 256 + wave * 64;

    // --- A fragments: 64 rows x K=256 in registers ---
    short8 a[4][8];
    #pragma unroll
    for (int q = 0; q < 4; ++q) {
        const unsigned short* base = zk + (size_t)(rb * 16 + wave * 4 + q) * 4096 + lane * 8;
        #pragma unroll
        for (int kk = 0; kk < 8; ++kk) a[q][kk] = *(const short8*)(base + kk * 512);
    }

    // --- packed row labels: labr_pk[q] holds 4 byte-labels (labels < 128) ---
    unsigned int labr_pk[4];
    #pragma unroll
    for (int q = 0; q < 4; ++q) {
        const int r0 = rowW + q * 16 + kgrp * 4;
        labr_pk[q] = (unsigned)labels[r0]
                   | ((unsigned)labels[r0 + 1] << 8)
                   | ((unsigned)labels[r0 + 2] << 16)
                   | ((unsigned)labels[r0 + 3] << 24);
    }

    // --- column labels for this block's 512 cols ---
    ldsLab[tid]       = labels[colStart + tid];
    ldsLab[256 + tid] = labels[colStart + 256 + tid];

    // --- staging: linear 32 KB copy (zk tile is contiguous, fragment-ordered)
    auto stage = [&](int t) {
        const char* src = (const char*)zk + (size_t)(colStart + t * 64) * 512
                        + wave * 1024 + lane * 16;
        char* dst = ldsB + (t & 1) * 32768 + wave * 1024;   // wave-uniform base
        #pragma unroll
        for (int r = 0; r < 8; ++r)
            __builtin_amdgcn_global_load_lds(
                (const __attribute__((address_space(1))) void*)(src + r * 4096),
                (__attribute__((address_space(3))) void*)(dst + r * 4096),
                16, 0, 0);
    };

    float se[16], ps[16];
    #pragma unroll
    for (int i = 0; i < 16; ++i) { se[i] = 0.f; ps[i] = 0.f; }

    stage(0);
    phase_barrier();

    #pragma unroll 1
    for (int t = 0; t < 8; ++t) {
        if (t < 7) stage(t + 1);                       // issue-early (T14)
        const char* base = ldsB + (t & 1) * 32768 + lane * 16;
        #pragma unroll
        for (int cf = 0; cf < 4; ++cf) {               // 4 x 16-col fragments
            short8 b[8];
            #pragma unroll
            for (int kk = 0; kk < 8; ++kk)
                b[kk] = *(const short8*)(base + cf * 8192 + kk * 1024);
            f32x4 c[4];
            #pragma unroll
            for (int q = 0; q < 4; ++q) c[q] = (f32x4){0.f, 0.f, 0.f, 0.f};
            #pragma unroll
            for (int kk = 0; kk < 8; ++kk) {
                c[0] = __builtin_amdgcn_mfma_f32_16x16x32_bf16(a[0][kk], b[kk], c[0], 0, 0, 0);
                c[1] = __builtin_amdgcn_mfma_f32_16x16x32_bf16(a[1][kk], b[kk], c[1], 0, 0, 0);
                c[2] = __builtin_amdgcn_mfma_f32_16x16x32_bf16(a[2][kk], b[kk], c[2], 0, 0, 0);
                c[3] = __builtin_amdgcn_mfma_f32_16x16x32_bf16(a[3][kk], b[kk], c[3], 0, 0, 0);
            }
            const unsigned int splat =
                (unsigned)ldsLab[t * 64 + cf * 16 + lrow] * 0x01010101u;
            #pragma unroll
            for (int q = 0; q < 4; ++q) {
                const unsigned int x = splat ^ labr_pk[q];
                #pragma unroll
                for (int j = 0; j < 4; ++j) {
                    se[q * 4 + j] += exp2f(c[q][j]);            // v_exp_f32
                    const bool m = ((x >> (8 * j)) & 0xFFu) == 0u;
                    ps[q * 4 + j] += m ? c[q][j] : 0.f;   // incl self; fixed in final
                }
            }
        }
        phase_barrier();
    }

    // --- reduce over the 16 col-lanes of each kgrp group; rows wave-exclusive ---
    #pragma unroll
    for (int i = 0; i < 16; ++i) {
        #pragma unroll
        for (int m = 1; m < 16; m <<= 1) {
            se[i] += __shfl_xor(se[i], m, 64);
            ps[i] += __shfl_xor(ps[i], m, 64);
        }
    }
    if (lrow == 0) {
        #pragma unroll
        for (int i = 0; i < 16; ++i) {
            const int r = rowW + (i >> 2) * 16 + kgrp * 4 + (i & 3);
            atomicAdd(&se_sum[r], se[i]);
            atomicAdd(&ps_sum[r], ps[i]);
        }
    }
}

// ---------------------------------------------------------------------------
// Kernel 3: single-block finalize. LDS label histogram + exact self removal:
// loss_r = log(se_r - exp2(sd_r)) - LN2*(ps_r - sd_r)/n_pos.
// ---------------------------------------------------------------------------
__global__ __launch_bounds__(1024)
void ntxent_final(const float* __restrict__ se_sum,
                  const float* __restrict__ ps_sum,
                  const float* __restrict__ sd,
                  const int* __restrict__ labels,
                  float* __restrict__ out) {
    __shared__ int hist[128];
    __shared__ float redc[16], redh[16];
    const int tid = threadIdx.x;
    if (tid < 128) hist[tid] = 0;
    __syncthreads();
    for (int i = tid; i < NROWS; i += 1024) atomicAdd(&hist[labels[i]], 1);
    __syncthreads();

    float contrib = 0.f, hp = 0.f;
    for (int i = tid; i < NROWS; i += 1024) {
        const int n = hist[labels[i]] - 1;
        if (n > 0) {
            const float s   = sd[i];
            const float see = se_sum[i] - exp2f(s);          // remove self exactly
            const float lse = __logf(see);
            contrib += lse - LN2 * (ps_sum[i] - s) / (float)n;
            hp += 1.0f;
        }
    }
    #pragma unroll
    for (int m = 32; m; m >>= 1) {
        contrib += __shfl_xor(contrib, m, 64);
        hp      += __shfl_xor(hp, m, 64);
    }
    if ((tid & 63) == 0) { redc[tid >> 6] = contrib; redh[tid >> 6] = hp; }
    __syncthreads();
    if (tid == 0) {
        float c = 0.f, h = 0.f;
        #pragma unroll
        for (int w = 0; w < 16; ++w) { c += redc[w]; h += redh[w]; }
        out[0] = c / fmaxf(h, 1.0f);
    }
}

extern "C" void kernel_launch(void* const* d_in, const int* in_sizes, int n_in,
                              void* d_out, int out_size, void* d_ws, size_t ws_size,
                              hipStream_t stream) {
    const float* latent = (const float*)d_in[0];
    const int*   labels = (const int*)d_in[1];
    float* out = (float*)d_out;

    unsigned short* zk = (unsigned short*)d_ws;                       // 4 MB
    char* p = (char*)d_ws + (size_t)NROWS * DIM * sizeof(unsigned short);
    float* se_sum = (float*)p;                                        // 32 KB
    float* ps_sum = (float*)(p + 32768);                              // 32 KB
    float* sd     = (float*)(p + 65536);                              // 32 KB (fully overwritten)

    hipMemsetAsync(p, 0, 65536, stream);
    normalize_kernel<<<NROWS / 4, 256, 0, stream>>>(latent, zk, sd);
    ntxent_main<<<512, 256, 0, stream>>>(zk, labels, se_sum, ps_sum);
    ntxent_final<<<1, 1024, 0, stream>>>(se_sum, ps_sum, sd, labels, out);
}

// Round 10
// 63.319 us; speedup vs baseline: 1.3330x; 1.2235x over previous
//
#include <hip/hip_runtime.h>
#include <hip/hip_bf16.h>

#define NROWS 8192
#define DIM   256
#define WROWS 64                   // rows per block (shared by all 4 waves)
#define NT    16                   // 16-col tiles per wave -> 256 cols/wave
// zk stores z * SQ_SCALE, SQ_SCALE^2 = 10*log2(e) = 14.4269504089 -> MFMA
// yields 14.43*cos, so exp(sim) = 2^(mfma_out) = v_exp_f32(mfma_out).
#define SQ_SCALE 3.798282387f
#define LN2      0.69314718056f    // 10 / 14.4269504089

typedef __attribute__((ext_vector_type(8))) short short8;
typedef __attribute__((ext_vector_type(4))) float f32x4;

__device__ __forceinline__ float bfbits2f(unsigned short u) {
    unsigned int x = ((unsigned int)u) << 16;
    float f; __builtin_memcpy(&f, &x, 4); return f;
}
__device__ __forceinline__ unsigned short f2bf(float x) {
    __hip_bfloat16 h = __float2bfloat16(x);
    unsigned short u; __builtin_memcpy(&u, &h, 2); return u;
}
// Raw 2^x: single VOP1. Input range here is [-14.5, 14.5] -> no denormal /
// overflow concerns, so the OCML guard sequence exp2f() drags in is pure waste.
__device__ __forceinline__ float exp2_raw(float x) {
    float r;
    asm("v_exp_f32 %0, %1" : "=v"(r) : "v"(x));
    return r;
}

// ---------------------------------------------------------------------------
// Kernel 1: L2-normalize rows fp32 -> bf16*SQ_SCALE into the fragment-native
// K-major layout: (row,d) -> (row>>4)*4096 + (d>>5)*512 + ((d>>3)&3)*128
//                           + (row&15)*8 + (d&7).
// Also stores the exact rounded self-dot sd[row] (fp32). No atomics.
// ---------------------------------------------------------------------------
__global__ __launch_bounds__(256)
void normalize_kernel(const float* __restrict__ latent,
                      unsigned short* __restrict__ zk,
                      float* __restrict__ sd_out) {
    const int wave = threadIdx.x >> 6, lane = threadIdx.x & 63;
    const int row = blockIdx.x * 4 + wave;
    const float4 v = ((const float4*)(latent + (size_t)row * DIM))[lane];
    float s = v.x * v.x + v.y * v.y + v.z * v.z + v.w * v.w;
    #pragma unroll
    for (int m = 32; m; m >>= 1) s += __shfl_xor(s, m, 64);
    const float sc = rsqrtf(s) * SQ_SCALE;
    ushort4 o;
    o.x = f2bf(v.x * sc); o.y = f2bf(v.y * sc);
    o.z = f2bf(v.z * sc); o.w = f2bf(v.w * sc);
    const int d0 = lane * 4;
    const size_t idx = (size_t)(row >> 4) * 4096 + (d0 >> 5) * 512
                     + ((d0 >> 3) & 3) * 128 + (row & 15) * 8 + (d0 & 7);
    *(ushort4*)(zk + idx) = o;
    const float r0 = bfbits2f(o.x), r1 = bfbits2f(o.y),
                r2 = bfbits2f(o.z), r3 = bfbits2f(o.w);
    float sd = r0 * r0 + r1 * r1 + r2 * r2 + r3 * r3;
    #pragma unroll
    for (int m = 32; m; m >>= 1) sd += __shfl_xor(sd, m, 64);
    if (lane == 0) sd_out[row] = sd;
}

// ---------------------------------------------------------------------------
// Kernel 2: fused sim reductions, registers only, desynced waves (no barriers
// in the sweep). 4 waves share the block's 64 rows (A = 128 VGPR each), each
// wave sweeps a different 256-col strip. No diagonal handling in-loop (self
// terms removed exactly in the final pass via sd). Raw v_exp_f32 epilogue.
// rb-major XCD pinning: bid%8 = rb%8 keeps a 512 KB A working set per L2.
// ---------------------------------------------------------------------------
__global__ __launch_bounds__(256, 2)
void ntxent_main(const unsigned short* __restrict__ zk,
                 const int* __restrict__ labels,
                 float* __restrict__ se_sum,
                 float* __restrict__ ps_sum) {
    __shared__ float rse[WROWS], rps[WROWS];
    const int tid  = threadIdx.x;
    const int wave = tid >> 6, lane = tid & 63;
    const int lrow = lane & 15, kgrp = lane >> 4;
    const int rb = blockIdx.x & 127, cb = blockIdx.x >> 7;   // XCD = bid%8 = rb%8
    const int rowW = rb * WROWS;
    const int strip = cb * 4 + wave;                          // 0..31
    const int colStart = strip * 256;

    if (tid < WROWS) { rse[tid] = 0.f; rps[tid] = 0.f; }

    // --- A fragments: 4 row-tiles x 8 k-chunks, contiguous 16B/lane ---
    short8 a[4][8];
    #pragma unroll
    for (int q = 0; q < 4; ++q) {
        const unsigned short* base = zk + (size_t)(rb * 4 + q) * 4096 + lane * 8;
        #pragma unroll
        for (int kk = 0; kk < 8; ++kk) a[q][kk] = *(const short8*)(base + kk * 512);
    }
    int labr[16];
    #pragma unroll
    for (int q = 0; q < 4; ++q)
        #pragma unroll
        for (int j = 0; j < 4; ++j)
            labr[q * 4 + j] = labels[rowW + q * 16 + kgrp * 4 + j];

    float se[16], ps[16];
    #pragma unroll
    for (int i = 0; i < 16; ++i) { se[i] = 0.f; ps[i] = 0.f; }

    const unsigned short* bbase = zk + (size_t)(strip * 16) * 4096 + lane * 8;
    short8 b[8];
    #pragma unroll
    for (int kk = 0; kk < 8; ++kk) b[kk] = *(const short8*)(bbase + kk * 512);

    #pragma unroll 1
    for (int t = 0; t < NT; ++t) {
        const int labc = labels[colStart + t * 16 + lrow];   // early; hides under MFMAs
        f32x4 c[4];
        #pragma unroll
        for (int q = 0; q < 4; ++q) c[q] = (f32x4){0.f, 0.f, 0.f, 0.f};
        #pragma unroll
        for (int kk = 0; kk < 8; ++kk) {
            c[0] = __builtin_amdgcn_mfma_f32_16x16x32_bf16(a[0][kk], b[kk], c[0], 0, 0, 0);
            c[1] = __builtin_amdgcn_mfma_f32_16x16x32_bf16(a[1][kk], b[kk], c[1], 0, 0, 0);
            c[2] = __builtin_amdgcn_mfma_f32_16x16x32_bf16(a[2][kk], b[kk], c[2], 0, 0, 0);
            c[3] = __builtin_amdgcn_mfma_f32_16x16x32_bf16(a[3][kk], b[kk], c[3], 0, 0, 0);
        }
        // prefetch next B tile (WAR after last use; latency hides under epilogue)
        if (t + 1 < NT) {
            const unsigned short* nb = bbase + (size_t)(t + 1) * 4096;
            #pragma unroll
            for (int kk = 0; kk < 8; ++kk) b[kk] = *(const short8*)(nb + kk * 512);
        }
        // lean epilogue: raw exp + add (se), cmp + cndmask + add (ps).
        #pragma unroll
        for (int q = 0; q < 4; ++q)
            #pragma unroll
            for (int j = 0; j < 4; ++j) {
                const int i = q * 4 + j;
                se[i] += exp2_raw(c[q][j]);
                ps[i] += (labc == labr[i]) ? c[q][j] : 0.f;  // incl self; fixed later
            }
    }

    // --- reduce over the 16 col-lanes of each kgrp group ---
    #pragma unroll
    for (int i = 0; i < 16; ++i) {
        #pragma unroll
        for (int m = 1; m < 16; m <<= 1) {
            se[i] += __shfl_xor(se[i], m, 64);
            ps[i] += __shfl_xor(ps[i], m, 64);
        }
    }
    __syncthreads();                 // rse/rps init done
    if (lrow == 0) {
        #pragma unroll
        for (int i = 0; i < 16; ++i) {
            const int rl = (i >> 2) * 16 + kgrp * 4 + (i & 3);
            atomicAdd(&rse[rl], se[i]);
            atomicAdd(&rps[rl], ps[i]);
        }
    }
    __syncthreads();
    if (tid < WROWS) {
        atomicAdd(&se_sum[rowW + tid], rse[tid]);
        atomicAdd(&ps_sum[rowW + tid], rps[tid]);
    }
}

// ---------------------------------------------------------------------------
// Kernel 3: single-block finalize. LDS label histogram + exact self removal:
// loss_r = log(se_r - exp2(sd_r)) - LN2*(ps_r - sd_r)/n_pos.
// ---------------------------------------------------------------------------
__global__ __launch_bounds__(1024)
void ntxent_final(const float* __restrict__ se_sum,
                  const float* __restrict__ ps_sum,
                  const float* __restrict__ sd,
                  const int* __restrict__ labels,
                  float* __restrict__ out) {
    __shared__ int hist[128];
    __shared__ float redc[16], redh[16];
    const int tid = threadIdx.x;
    if (tid < 128) hist[tid] = 0;
    __syncthreads();
    for (int i = tid; i < NROWS; i += 1024) atomicAdd(&hist[labels[i]], 1);
    __syncthreads();

    float contrib = 0.f, hp = 0.f;
    for (int i = tid; i < NROWS; i += 1024) {
        const int n = hist[labels[i]] - 1;
        if (n > 0) {
            const float s   = sd[i];
            const float see = se_sum[i] - exp2f(s);          // remove self exactly
            const float lse = __logf(see);
            contrib += lse - LN2 * (ps_sum[i] - s) / (float)n;
            hp += 1.0f;
        }
    }
    #pragma unroll
    for (int m = 32; m; m >>= 1) {
        contrib += __shfl_xor(contrib, m, 64);
        hp      += __shfl_xor(hp, m, 64);
    }
    if ((tid & 63) == 0) { redc[tid >> 6] = contrib; redh[tid >> 6] = hp; }
    __syncthreads();
    if (tid == 0) {
        float c = 0.f, h = 0.f;
        #pragma unroll
        for (int w = 0; w < 16; ++w) { c += redc[w]; h += redh[w]; }
        out[0] = c / fmaxf(h, 1.0f);
    }
}

extern "C" void kernel_launch(void* const* d_in, const int* in_sizes, int n_in,
                              void* d_out, int out_size, void* d_ws, size_t ws_size,
                              hipStream_t stream) {
    const float* latent = (const float*)d_in[0];
    const int*   labels = (const int*)d_in[1];
    float* out = (float*)d_out;

    unsigned short* zk = (unsigned short*)d_ws;                       // 4 MB
    char* p = (char*)d_ws + (size_t)NROWS * DIM * sizeof(unsigned short);
    float* se_sum = (float*)p;                                        // 32 KB
    float* ps_sum = (float*)(p + 32768);                              // 32 KB
    float* sd     = (float*)(p + 65536);                              // 32 KB (fully overwritten)

    hipMemsetAsync(p, 0, 65536, stream);
    normalize_kernel<<<NROWS / 4, 256, 0, stream>>>(latent, zk, sd);
    ntxent_main<<<1024, 256, 0, stream>>>(zk, labels, se_sum, ps_sum);
    ntxent_final<<<1, 1024, 0, stream>>>(se_sum, ps_sum, sd, labels, out);
}